// Round 7
// baseline (269.292 us; speedup 1.0000x reference)
//
#include <hip/hip_runtime.h>
#include <math.h>

#define NLAYERS 2
#define HID 128
#define FFND 256
#define NH 4
#define SEQL 2048
#define HD 32
#define HDV 64
#define VD 256
#define NBATCH 2
#define MROWS (NBATCH*SEQL)   // 4096
#define NCAT 768              // Q(128) | K(128) | V(256) | G(256)
#define NCHUNK 32             // SEQL / 64

// ---------------------------------------------------------------------------
// xPos tables: sinQ/cosQ (scaled) and sinK/cosK (inverse-scaled), SEQ x 16
// ---------------------------------------------------------------------------
__global__ __launch_bounds__(256) void tabs_kernel(float* __restrict__ tabs)
{
  int idx = blockIdx.x * 256 + threadIdx.x;   // s*16 + i
  int s = idx >> 4, i = idx & 15;
  float inv_freq = powf(10000.f, -(float)i * (1.f/16.f));
  float ang = (float)s * inv_freq;
  float sv  = ((float)(2*i) + 0.4f*32.f) / (1.4f*32.f);
  float sc  = powf(sv, (float)s * (1.f/512.f));
  float sn = sinf(ang), cs = cosf(ang);
  tabs[idx]          = sn * sc;   // sinQ
  tabs[32768 + idx]  = cs * sc;   // cosQ
  tabs[65536 + idx]  = sn / sc;   // sinK
  tabs[98304 + idx]  = cs / sc;   // cosK
}

// ---------------------------------------------------------------------------
// LayerNorm over rows of 128; one wave per row, 4 rows per block.
// ---------------------------------------------------------------------------
__global__ __launch_bounds__(256) void ln_rows_kernel(
    const float* __restrict__ X, const float* __restrict__ g,
    const float* __restrict__ b, float* __restrict__ O)
{
  int wid = threadIdx.x >> 6, lane = threadIdx.x & 63;
  int row = blockIdx.x * 4 + wid;
  const float* x = X + (size_t)row * HID;
  float v0 = x[lane], v1 = x[lane + 64];
  float s = v0 + v1;
  #pragma unroll
  for (int o = 32; o; o >>= 1) s += __shfl_xor(s, o);
  float mu = s * (1.f/128.f);
  float d0 = v0 - mu, d1 = v1 - mu;
  float q = d0*d0 + d1*d1;
  #pragma unroll
  for (int o = 32; o; o >>= 1) q += __shfl_xor(q, o);
  float rs = rsqrtf(q * (1.f/128.f) + 1e-5f);
  O[(size_t)row*HID + lane]      = d0 * rs * g[lane]      + b[lane];
  O[(size_t)row*HID + lane + 64] = d1 * rs * g[lane + 64] + b[lane + 64];
}

// ---------------------------------------------------------------------------
// QKVG projection + xPos. 64 threads (1 wave), tile 64x64, micro 8x8, K=128
// LDS-resident A (transposed, XOR-swizzled). B read directly from the weight
// tensors (no pack), double-buffered through registers.
// Grid (64, 12) = 768 blocks = 3 waves/CU. LDS 43.5 KB -> 3 blocks/CU.
// ---------------------------------------------------------------------------
__global__ __launch_bounds__(64) void gemm_qkvg(
    const float* __restrict__ H,
    const float* __restrict__ WQ, const float* __restrict__ WK,
    const float* __restrict__ WV, const float* __restrict__ WG,
    const float* __restrict__ tabs, float* __restrict__ C, int l)
{
  __shared__ float As[128][68];   // [k][row ^ 8*((k>>2)&7)]
  __shared__ float Bs[32][68];
  int tid = threadIdx.x;
  int tx = tid & 7, ty = tid >> 3;          // cols 8*tx, rows 8*ty
  int rb = blockIdx.x * 64, nb = blockIdx.y * 64;

  // ---- per-block B source (uniform): base + k*kstr + coff(n) ----
  const float* wbase; int kstr;
  if (nb < 128)      { wbase = WQ + (size_t)l*NH*HID*HD;  kstr = HD;  }
  else if (nb < 256) { wbase = WK + (size_t)l*NH*HID*HD;  kstr = HD;  }
  else if (nb < 512) { wbase = WV + (size_t)l*NH*HID*HDV; kstr = HDV; }
  else               { wbase = WG + (size_t)l*HID*VD;     kstr = VD;  }
  int coffs[8];
  #pragma unroll
  for (int it = 0; it < 8; it++) {
    int nq = (it*64 + tid) & 15;
    int n = nb + 4*nq;
    int co;
    if (nb < 128)      co = (n>>5)*(HID*HD) + (n&31);
    else if (nb < 256) { int m = n-128; co = (m>>5)*(HID*HD)  + (m&31); }
    else if (nb < 512) { int m = n-256; co = (m>>6)*(HID*HDV) + (m&63); }
    else               co = n - 512;
    coffs[it] = co;
  }

  // ---- stage A (LN'd rows) transposed + swizzled ----
  #pragma unroll
  for (int it = 0; it < 32; it++) {
    int idx = it*64 + tid;
    int row = idx >> 5, f4q = idx & 31;
    float4 a4 = *(const float4*)(H + (size_t)(rb+row)*HID + 4*f4q);
    int rs = row ^ (8*(f4q & 7));
    As[4*f4q+0][rs] = a4.x; As[4*f4q+1][rs] = a4.y;
    As[4*f4q+2][rs] = a4.z; As[4*f4q+3][rs] = a4.w;
  }

  // ---- B prefetch for ks=0 ----
  float4 pre[8];
  #pragma unroll
  for (int it = 0; it < 8; it++) {
    int kk = ((it*64 + tid) >> 4);
    pre[it] = *(const float4*)(wbase + (size_t)kk*kstr + coffs[it]);
  }

  float acc[8][8];
  #pragma unroll
  for (int i=0;i<8;i++)
    #pragma unroll
    for (int j=0;j<8;j++) acc[i][j] = 0.f;

  for (int ks = 0; ks < 128; ks += 32) {
    __syncthreads();
    #pragma unroll
    for (int it = 0; it < 8; it++) {
      int idx = it*64 + tid;
      int kk = idx >> 4, nq = idx & 15;
      *(float4*)&Bs[kk][4*nq] = pre[it];
    }
    __syncthreads();
    if (ks + 32 < 128) {
      #pragma unroll
      for (int it = 0; it < 8; it++) {
        int kk = ((it*64 + tid) >> 4);
        pre[it] = *(const float4*)(wbase + (size_t)(ks+32+kk)*kstr + coffs[it]);
      }
    }
    #pragma unroll
    for (int kk = 0; kk < 32; kk++) {
      int k = ks + kk;
      int sw = (8*ty) ^ (8*((k>>2)&7));
      float a[8], b[8];
      *(float4*)(a)   = *(const float4*)&As[k][sw];
      *(float4*)(a+4) = *(const float4*)&As[k][sw + 4];
      *(float4*)(b)   = *(const float4*)&Bs[kk][8*tx];
      *(float4*)(b+4) = *(const float4*)&Bs[kk][8*tx + 4];
      #pragma unroll
      for (int i=0;i<8;i++)
        #pragma unroll
        for (int j=0;j<8;j++)
          acc[i][j] = fmaf(a[i], b[j], acc[i][j]);
    }
  }

  // ---- epilogue: xPos rotate (Q / K cols), store 2 float4 per row ----
  #pragma unroll
  for (int i=0;i<8;i++) {
    int row = rb + 8*ty + i;
    int cb = nb + 8*tx;
    float o[8];
    #pragma unroll
    for (int j=0;j<8;j++) o[j] = acc[i][j];
    if (nb < 256) {
      bool isK = (nb >= 128);
      const float* sn_t = tabs + (isK ? 65536 : 0);
      const float* cs_t = tabs + (isK ? 98304 : 32768);
      int s = row & (SEQL - 1);
      #pragma unroll
      for (int p = 0; p < 4; p++) {
        int i0 = ((cb + 2*p) & 31) >> 1;
        float sn = sn_t[s*16 + i0], cs = cs_t[s*16 + i0];
        float x1 = o[2*p], x2 = o[2*p+1];
        o[2*p]   = x1*cs - x2*sn;
        o[2*p+1] = x2*cs + x1*sn;
      }
    }
    *(float4*)(C + (size_t)row*NCAT + cb)     = *(float4*)(o);
    *(float4*)(C + (size_t)row*NCAT + cb + 4) = *(float4*)(o + 4);
  }
}

// ---------------------------------------------------------------------------
// FFN1: 64 threads, tile 32x64, micro 4x8, K=128 LDS-resident A.
// Grid (128, 4) = 512 blocks = 2 waves/CU. bias + exact gelu.
// ---------------------------------------------------------------------------
__global__ __launch_bounds__(64) void gemm_ffn1(
    const float* __restrict__ H, const float* __restrict__ Bw,
    const float* __restrict__ bias, float* __restrict__ C)
{
  __shared__ float As[128][36];   // [k][row ^ 4*((k>>2)&7)]
  __shared__ float Bs[32][68];
  int tid = threadIdx.x;
  int tx = tid & 7, ty = tid >> 3;          // cols 8*tx, rows 4*ty
  int rb = blockIdx.x * 32, nb = blockIdx.y * 64;

  #pragma unroll
  for (int it = 0; it < 16; it++) {         // A: 32 rows x 128 k
    int idx = it*64 + tid;
    int row = idx >> 5, f4q = idx & 31;
    float4 a4 = *(const float4*)(H + (size_t)(rb+row)*HID + 4*f4q);
    int rs = row ^ (4*(f4q & 7));
    As[4*f4q+0][rs] = a4.x; As[4*f4q+1][rs] = a4.y;
    As[4*f4q+2][rs] = a4.z; As[4*f4q+3][rs] = a4.w;
  }

  float4 pre[8];
  #pragma unroll
  for (int it = 0; it < 8; it++) {
    int idx = it*64 + tid;
    int kk = idx >> 4, nq = idx & 15;
    pre[it] = *(const float4*)(Bw + (size_t)kk*FFND + nb + 4*nq);
  }

  float acc[4][8];
  #pragma unroll
  for (int i=0;i<4;i++)
    #pragma unroll
    for (int j=0;j<8;j++) acc[i][j] = 0.f;

  for (int ks = 0; ks < 128; ks += 32) {
    __syncthreads();
    #pragma unroll
    for (int it = 0; it < 8; it++) {
      int idx = it*64 + tid;
      int kk = idx >> 4, nq = idx & 15;
      *(float4*)&Bs[kk][4*nq] = pre[it];
    }
    __syncthreads();
    if (ks + 32 < 128) {
      #pragma unroll
      for (int it = 0; it < 8; it++) {
        int idx = it*64 + tid;
        int kk = idx >> 4, nq = idx & 15;
        pre[it] = *(const float4*)(Bw + (size_t)(ks+32+kk)*FFND + nb + 4*nq);
      }
    }
    #pragma unroll
    for (int kk = 0; kk < 32; kk++) {
      int k = ks + kk;
      float a[4], b[8];
      *(float4*)a     = *(const float4*)&As[k][(4*ty) ^ (4*((k>>2)&7))];
      *(float4*)(b)   = *(const float4*)&Bs[kk][8*tx];
      *(float4*)(b+4) = *(const float4*)&Bs[kk][8*tx + 4];
      #pragma unroll
      for (int i=0;i<4;i++)
        #pragma unroll
        for (int j=0;j<8;j++)
          acc[i][j] = fmaf(a[i], b[j], acc[i][j]);
    }
  }

  #pragma unroll
  for (int i=0;i<4;i++) {
    int row = rb + 4*ty + i;
    int cb = nb + 8*tx;
    float o[8];
    #pragma unroll
    for (int j=0;j<8;j++) {
      float v = acc[i][j] + bias[cb + j];
      o[j] = 0.5f * v * (1.f + erff(v * 0.70710678118f));
    }
    *(float4*)(C + (size_t)row*FFND + cb)     = *(float4*)(o);
    *(float4*)(C + (size_t)row*FFND + cb + 4) = *(float4*)(o + 4);
  }
}

// ---------------------------------------------------------------------------
// Narrow GEMM, N=128, K=256 (WO, FFN2): 128 threads, tile 64x32, micro 4x4.
// Grid (64, 4) = 256 blocks = 2 waves/CU.
// ---------------------------------------------------------------------------
template<bool BIAS>
__global__ __launch_bounds__(128) void gemm_nar(
    const float* __restrict__ A, const float* __restrict__ Bw,
    const float* __restrict__ bias, const float* __restrict__ Rsd,
    float* __restrict__ C)
{
  __shared__ float As[64][68];    // [k][row ^ 4*((k>>2)&7)]
  __shared__ float Bs[64][36];
  int tid = threadIdx.x;
  int tx = tid & 7, ty = tid >> 3;          // cols 4*tx, rows 4*ty (ty 0..15)
  int rb = blockIdx.x * 64, nb = blockIdx.y * 32;

  float acc[4][4];
  #pragma unroll
  for (int i=0;i<4;i++)
    #pragma unroll
    for (int j=0;j<4;j++) acc[i][j] = 0.f;

  for (int ks = 0; ks < 256; ks += 64) {
    #pragma unroll
    for (int it = 0; it < 8; it++) {        // A: 64 rows x 64 k
      int idx = it*128 + tid;
      int row = idx >> 4, kq = idx & 15;
      float4 a4 = *(const float4*)(A + (size_t)(rb+row)*256 + ks + 4*kq);
      int rs = row ^ (4*(kq & 7));
      As[4*kq+0][rs] = a4.x; As[4*kq+1][rs] = a4.y;
      As[4*kq+2][rs] = a4.z; As[4*kq+3][rs] = a4.w;
    }
    #pragma unroll
    for (int it = 0; it < 4; it++) {        // B: 64 k x 32 n
      int idx = it*128 + tid;
      int kk = idx >> 3, nq = idx & 7;
      *(float4*)&Bs[kk][4*nq] = *(const float4*)(Bw + (size_t)(ks+kk)*HID + nb + 4*nq);
    }
    __syncthreads();
    #pragma unroll
    for (int kk = 0; kk < 64; kk++) {
      float a[4], b[4];
      *(float4*)a = *(const float4*)&As[kk][(4*ty) ^ (4*((kk>>2)&7))];
      *(float4*)b = *(const float4*)&Bs[kk][4*tx];
      #pragma unroll
      for (int i=0;i<4;i++)
        #pragma unroll
        for (int j=0;j<4;j++)
          acc[i][j] = fmaf(a[i], b[j], acc[i][j]);
    }
    __syncthreads();
  }

  #pragma unroll
  for (int i=0;i<4;i++) {
    int row = rb + 4*ty + i;
    int cb = nb + 4*tx;
    float o[4];
    #pragma unroll
    for (int j=0;j<4;j++) {
      float v = acc[i][j];
      if (BIAS) v += bias[cb + j];
      v += Rsd[(size_t)row*HID + cb + j];
      o[j] = v;
    }
    *(float4*)(C + (size_t)row*HID + cb) = *(float4*)o;
  }
}

// ---------------------------------------------------------------------------
// Retention pass A: per (b,h,chunk) decayed KV summary (32x64), 512 threads
// ---------------------------------------------------------------------------
__global__ __launch_bounds__(512) void ret_kv_kernel(
    const float* __restrict__ QKVG, float* __restrict__ Asum)
{
  int bh = blockIdx.x >> 5;       // b*4+h
  int c  = blockIdx.x & 31;
  int b = bh >> 2, h = bh & 3;
  float t0 = logf(1.f/32.f) + (float)h * (logf(1.f/512.f) - logf(1.f/32.f)) * (1.f/3.f);
  float gamma = 1.f - expf(t0);
  float lg = logf(gamma);

  __shared__ float Ks[64][36];
  __shared__ float Vs[64][68];
  __shared__ float wt[64];

  int tid = threadIdx.x;
  int c0 = c * 64;
  const float* base = QKVG + (size_t)(b * SEQL) * NCAT;

  {
    int row = tid >> 3, eq = tid & 7;
    *(float4*)&Ks[row][4*eq] =
        *(const float4*)(base + (size_t)(c0+row)*NCAT + 128 + h*32 + 4*eq);
  }
  #pragma unroll
  for (int it = 0; it < 2; it++) {
    int idx = it*512 + tid;
    int row = idx >> 4, vq = idx & 15;
    *(float4*)&Vs[row][4*vq] =
        *(const float4*)(base + (size_t)(c0+row)*NCAT + 256 + h*64 + 4*vq);
  }
  if (tid < 64) wt[tid] = __expf(lg * (float)(64 - tid));
  __syncthreads();

  int e = tid >> 4, v4 = (tid & 15) * 4;
  float a0[4] = {0,0,0,0};
  #pragma unroll 8
  for (int t = 0; t < 64; t++) {
    float kw = Ks[t][e] * wt[t];
    float4 v0 = *(const float4*)&Vs[t][v4];
    a0[0] = fmaf(kw, v0.x, a0[0]); a0[1] = fmaf(kw, v0.y, a0[1]);
    a0[2] = fmaf(kw, v0.z, a0[2]); a0[3] = fmaf(kw, v0.w, a0[3]);
  }
  *(float4*)(Asum + ((size_t)(bh*NCHUNK + c))*2048 + e*64 + v4) = *(float4*)a0;
}

// ---------------------------------------------------------------------------
// Retention pass C + fused GroupNorm + SiLU gate. 512 threads, micro 4x2.
// ---------------------------------------------------------------------------
__global__ __launch_bounds__(512) void ret_out_kernel(
    const float* __restrict__ QKVG, const float* __restrict__ Asum,
    const float* __restrict__ gn_g, const float* __restrict__ gn_b,
    float* __restrict__ Gated)
{
  int bh = blockIdx.x >> 5;
  int c  = blockIdx.x & 31;
  int b = bh >> 2, h = bh & 3;
  float t0 = logf(1.f/32.f) + (float)h * (logf(1.f/512.f) - logf(1.f/32.f)) * (1.f/3.f);
  float gamma = 1.f - expf(t0);
  float lg = logf(gamma);
  float g64 = __expf(lg * 64.f);

  __shared__ float Qs[64][36];
  __shared__ float Ks[64][36];
  __shared__ float Vs[64][68];
  __shared__ float Ss[64][68];
  __shared__ float Sc[32][68];

  int tid = threadIdx.x;
  int tx2 = tid & 31, ty2 = tid >> 5;   // cols 2*tx2, rows 4*ty2
  int c0 = c * 64;
  const float* base = QKVG + (size_t)(b * SEQL) * NCAT;

  {
    int row = tid >> 3, eq = tid & 7;
    *(float4*)&Qs[row][4*eq] =
        *(const float4*)(base + (size_t)(c0+row)*NCAT + h*32 + 4*eq);
    int esw = (4*eq) ^ (4*((row >> 2) & 7));
    *(float4*)&Ks[row][esw] =
        *(const float4*)(base + (size_t)(c0+row)*NCAT + 128 + h*32 + 4*eq);
  }
  #pragma unroll
  for (int it = 0; it < 2; it++) {
    int idx = it*512 + tid;
    int row = idx >> 4, vq = idx & 15;
    *(float4*)&Vs[row][4*vq] =
        *(const float4*)(base + (size_t)(c0+row)*NCAT + 256 + h*64 + 4*vq);
  }

  {                                           // cross-chunk state combine
    int e = tid >> 4, v4 = (tid & 15) * 4;
    float s0[4] = {0,0,0,0};
    float w = 1.f;
    const float* ab = Asum + ((size_t)bh*NCHUNK)*2048 + e*64 + v4;
    for (int cp = c-1; cp >= 0; --cp) {
      const float* ap = ab + (size_t)cp*2048;
      float4 x0 = *(const float4*)ap;
      s0[0] = fmaf(w, x0.x, s0[0]); s0[1] = fmaf(w, x0.y, s0[1]);
      s0[2] = fmaf(w, x0.z, s0[2]); s0[3] = fmaf(w, x0.w, s0[3]);
      w *= g64;
    }
    *(float4*)&Sc[e][v4] = *(float4*)s0;
  }
  __syncthreads();

  // intra-chunk S = Q K^T (.) decay  -> Ss
  float sacc[4][2];
  #pragma unroll
  for (int i=0;i<4;i++) { sacc[i][0]=0.f; sacc[i][1]=0.f; }
  #pragma unroll
  for (int e = 0; e < 32; e += 4) {
    float qv[4][4], kv[2][4];
    #pragma unroll
    for (int i=0;i<4;i++)
      *(float4*)qv[i] = *(const float4*)&Qs[4*ty2+i][e];
    #pragma unroll
    for (int j=0;j<2;j++) {
      int kr = 2*tx2 + j;
      *(float4*)kv[j] = *(const float4*)&Ks[kr][e ^ (4*((kr>>2)&7))];
    }
    #pragma unroll
    for (int i=0;i<4;i++)
      #pragma unroll
      for (int j=0;j<2;j++)
        sacc[i][j] = fmaf(qv[i][0], kv[j][0],
                     fmaf(qv[i][1], kv[j][1],
                     fmaf(qv[i][2], kv[j][2],
                     fmaf(qv[i][3], kv[j][3], sacc[i][j]))));
  }
  #pragma unroll
  for (int i=0;i<4;i++) {
    int sl = 4*ty2 + i;
    float o2[2];
    #pragma unroll
    for (int j=0;j<2;j++) {
      int dr = sl - (2*tx2 + j);
      float w = (dr >= 0) ? __expf(lg * (float)dr) : 0.f;
      o2[j] = sacc[i][j] * w;
    }
    *(float2*)&Ss[sl][2*tx2] = *(float2*)o2;
  }

  // cross term: acc = diag(gamma^sl) * (Q @ Sc)
  float acc[4][2];
  #pragma unroll
  for (int i=0;i<4;i++) { acc[i][0]=0.f; acc[i][1]=0.f; }
  #pragma unroll
  for (int e = 0; e < 32; e += 4) {
    float qv[4][4], sv[4][2];
    #pragma unroll
    for (int i=0;i<4;i++)
      *(float4*)qv[i] = *(const float4*)&Qs[4*ty2+i][e];
    #pragma unroll
    for (int m=0;m<4;m++)
      *(float2*)sv[m] = *(const float2*)&Sc[e+m][2*tx2];
    #pragma unroll
    for (int i=0;i<4;i++)
      #pragma unroll
      for (int j=0;j<2;j++)
        acc[i][j] = fmaf(qv[i][0], sv[0][j],
                    fmaf(qv[i][1], sv[1][j],
                    fmaf(qv[i][2], sv[2][j],
                    fmaf(qv[i][3], sv[3][j], acc[i][j]))));
  }
  #pragma unroll
  for (int i=0;i<4;i++) {
    float gr = __expf(lg * (float)(4*ty2 + i));
    acc[i][0] *= gr; acc[i][1] *= gr;
  }
  __syncthreads();

  // Y += Ss @ V
  #pragma unroll
  for (int t = 0; t < 64; t += 4) {
    float sv[4][4], vv[4][2];
    #pragma unroll
    for (int i=0;i<4;i++)
      *(float4*)sv[i] = *(const float4*)&Ss[4*ty2+i][t];
    #pragma unroll
    for (int m=0;m<4;m++)
      *(float2*)vv[m] = *(const float2*)&Vs[t+m][2*tx2];
    #pragma unroll
    for (int i=0;i<4;i++)
      #pragma unroll
      for (int j=0;j<2;j++)
        acc[i][j] = fmaf(sv[i][0], vv[0][j],
                    fmaf(sv[i][1], vv[1][j],
                    fmaf(sv[i][2], vv[2][j],
                    fmaf(sv[i][3], vv[3][j], acc[i][j]))));
  }

  // fused GroupNorm (per head, 64 cols over 32 lanes) + SiLU gate
  #pragma unroll
  for (int i=0;i<4;i++) {
    float s1 = acc[i][0] + acc[i][1];
    #pragma unroll
    for (int o = 16; o; o >>= 1) s1 += __shfl_xor(s1, o);
    float mu = s1 * (1.f/64.f);
    float q = 0.f;
    #pragma unroll
    for (int j=0;j<2;j++) { float d = acc[i][j] - mu; q += d*d; }
    #pragma unroll
    for (int o = 16; o; o >>= 1) q += __shfl_xor(q, o);
    float rs = rsqrtf(q * (1.f/64.f) + 1e-5f);
    int row = b*SEQL + c0 + 4*ty2 + i;
    float2 g2 = *(const float2*)(QKVG + (size_t)row*NCAT + 512 + h*64 + 2*tx2);
    float gv[2] = {g2.x, g2.y};
    float o2[2];
    #pragma unroll
    for (int j=0;j<2;j++) {
      int col = h*64 + 2*tx2 + j;
      float yn = (acc[i][j] - mu) * rs * gn_g[col] + gn_b[col];
      float g = gv[j];
      float sig = 1.f / (1.f + __expf(-g));
      o2[j] = g * sig * yn;
    }
    *(float2*)(Gated + (size_t)row*VD + h*64 + 2*tx2) = *(float2*)o2;
  }
}

// ---------------------------------------------------------------------------
extern "C" void kernel_launch(void* const* d_in, const int* in_sizes, int n_in,
                              void* d_out, int out_size, void* d_ws, size_t ws_size,
                              hipStream_t stream)
{
  (void)in_sizes; (void)n_in; (void)out_size; (void)ws_size;
  const float* x_in  = (const float*)d_in[0];
  const float* ln1_g = (const float*)d_in[1];
  const float* ln1_b = (const float*)d_in[2];
  const float* ln2_g = (const float*)d_in[3];
  const float* ln2_b = (const float*)d_in[4];
  const float* WQ    = (const float*)d_in[5];
  const float* WK    = (const float*)d_in[6];
  const float* WV    = (const float*)d_in[7];
  const float* WG    = (const float*)d_in[8];
  const float* WO    = (const float*)d_in[9];
  const float* gn_g  = (const float*)d_in[10];
  const float* gn_b  = (const float*)d_in[11];
  const float* w1    = (const float*)d_in[12];
  const float* b1    = (const float*)d_in[13];
  const float* w2    = (const float*)d_in[14];
  const float* b2    = (const float*)d_in[15];
  float* out = (float*)d_out;
  float* ws  = (float*)d_ws;

  float* tabs = ws;                       // 131072
  float* Hbuf = tabs + 131072;            // 524288 (LN out, reused LN1/LN2)
  float* QKVG = Hbuf + 524288;            // 3145728
  float* Asum = QKVG + 3145728;           // 524288
  float* Gt   = Asum + 524288;            // 1048576
  float* Yres = Gt   + 1048576;           // 524288
  float* Mid  = Yres + 524288;            // 1048576

  tabs_kernel<<<128, 256, 0, stream>>>(tabs);

  for (int l = 0; l < NLAYERS; l++) {
    const float* xl = (l == 0) ? x_in : out;
    // LN1
    ln_rows_kernel<<<MROWS/4, 256, 0, stream>>>(xl, ln1_g + l*HID, ln1_b + l*HID, Hbuf);
    // QKVG projection + xPos (weights read direct; grid 768, 1-wave blocks)
    gemm_qkvg<<<dim3(MROWS/64, NCAT/64), 64, 0, stream>>>(
        Hbuf, WQ, WK, WV, WG, tabs, QKVG, l);
    // retention
    ret_kv_kernel<<<256, 512, 0, stream>>>(QKVG, Asum);
    ret_out_kernel<<<256, 512, 0, stream>>>(QKVG, Asum, gn_g + l*VD, gn_b + l*VD, Gt);
    // WO projection + residual
    gemm_nar<false><<<dim3(MROWS/64, HID/32), 128, 0, stream>>>(
        Gt, WO + l*VD*HID, nullptr, xl, Yres);
    // LN2
    ln_rows_kernel<<<MROWS/4, 256, 0, stream>>>(Yres, ln2_g + l*HID, ln2_b + l*HID, Hbuf);
    // FFN1 + bias + gelu
    gemm_ffn1<<<dim3(MROWS/32, FFND/64), 64, 0, stream>>>(
        Hbuf, w1 + l*HID*FFND, b1 + l*FFND, Mid);
    // FFN2 + bias + residual
    gemm_nar<true><<<dim3(MROWS/64, HID/32), 128, 0, stream>>>(
        Mid, w2 + l*FFND*HID, b2 + l*HID, Yres, out);
  }
}